// Round 11
// baseline (298.106 us; speedup 1.0000x reference)
//
#include <hip/hip_runtime.h>
#include <hip/hip_fp16.h>
#include <hip/hip_cooperative_groups.h>

#define B_ 2
#define C_ 32
#define H_ 256
#define W_ 256
#define K_ 4
#define HW_ (H_ * W_)

typedef float floatx4 __attribute__((ext_vector_type(4)));
typedef unsigned int uintx4 __attribute__((ext_vector_type(4)));

namespace cg = cooperative_groups;

// ---------------------------------------------------------------------------
// Single cooperative kernel, 2048 blocks x 128 threads (all co-resident:
// ~10.5KB LDS, VGPR<=128 -> 8 blocks/CU needed, ~15 possible).
// Stage A: transpose+fp16-convert this block's 64-px slice of v into vt
//          (64B/pixel lines) AND phase-1 (weights+offsets, packed 4B/tap).
// grid.sync (device-scope release: nt vt stores visible across XCD L2s).
// Stage B: 36 random 64B gathers/query from vt (XCD-batch partitioned so
//          each XCD's 4MiB slice is L2-resident), direct nt stores.
// R10 model: stage B is at the per-CU random-line wall (~0.23 lines/cy/CU,
// MSHR x L2-latency); this round removes the serial transpose + phase-1
// time in front of it.
// ---------------------------------------------------------------------------
__global__ __launch_bounds__(128, 4) void fused_kernel(
    const float* __restrict__ v, const float* __restrict__ cost_map,
    const int* __restrict__ shift_map, unsigned int* __restrict__ vt,
    float* __restrict__ out) {
  __shared__ union U {
    float tile[32][65];       // stage A transpose staging (8320B)
    unsigned int ew[64][37];  // packed taps: (line_u16<<16)|fp16(e) (9472B)
  } u;
  __shared__ float lds_part[64][4];  // softmax partials per (px,k)

  int t = threadIdx.x;
  // XCD-aware decomposition (empirical round-robin: XCD = blockIdx % 8).
  int bid = blockIdx.x;            // 0..2047
  int xcd = bid & 7;
  int b = xcd >> 2;                // XCDs 0-3 -> batch 0, 4-7 -> batch 1
  int workid = ((xcd & 3) << 8) + (bid >> 3);  // 0..1023
  int y = workid >> 2;             // 4 tiles of 64px per row
  int x0 = (workid & 3) << 6;
  int pix0 = b * HW_ + y * W_ + x0;

  // ---- stage A1: transpose 64-px slice of v -> LDS tile -------------------
  {
    const float* vb = v + (size_t)b * C_ * HW_ + y * W_ + x0;
    int cc = t >> 4;       // 0..7
    int lf = t & 15;       // 0..15 -> px = lf*4
#pragma unroll
    for (int it = 0; it < 4; ++it) {
      int c = cc + it * 8;
      floatx4 r = __builtin_nontemporal_load(
          (const floatx4*)&vb[(size_t)c * HW_ + lf * 4]);
      u.tile[c][lf * 4 + 0] = r.x;
      u.tile[c][lf * 4 + 1] = r.y;
      u.tile[c][lf * 4 + 2] = r.z;
      u.tile[c][lf * 4 + 3] = r.w;
    }
  }
  __syncthreads();
  // ---- stage A2: pack fp16, write vt (64B/pixel, coalesced nt stores) -----
  {
    int px = t >> 1;       // 0..63
    int half = t & 1;      // channels half*16 .. half*16+15
    int cbase = half * 16;
    unsigned int w[8];
#pragma unroll
    for (int j = 0; j < 8; ++j) {
      __half2 h2 = __floats2half2_rn(u.tile[cbase + 2 * j][px],
                                     u.tile[cbase + 2 * j + 1][px]);
      __builtin_memcpy(&w[j], &h2, 4);
    }
    uintx4 o0, o1;
    o0.x = w[0]; o0.y = w[1]; o0.z = w[2]; o0.w = w[3];
    o1.x = w[4]; o1.y = w[5]; o1.z = w[6]; o1.w = w[7];
    char* dst = (char*)vt + (((size_t)(pix0 + px)) << 6) + half * 32;
    __builtin_nontemporal_store(o0, (uintx4*)dst);
    __builtin_nontemporal_store(o1, (uintx4*)(dst + 16));
  }
  __syncthreads();  // tile reads done before ew overwrites the union

  // ---- stage A3: phase-1 weights + packed offsets -------------------------
  {
    int k = t >> 5;        // 4 k-groups of 32 lanes
    int lane32 = t & 31;
    const float* cm = cost_map + (size_t)(b * K_ + k) * HW_;
    const int* s0 = shift_map + (size_t)((b * 2 + 0) * K_ + k) * HW_;
    const int* s1 = shift_map + (size_t)((b * 2 + 1) * K_ + k) * HW_;
#pragma unroll
    for (int p2 = 0; p2 < 2; ++p2) {
      int px = lane32 + 32 * p2;
      int x = x0 + px;
      float psum = 0.f;
#pragma unroll
      for (int di = 0; di < 3; ++di) {
        int ny = y + di - 1;
        bool yin = (unsigned)ny < (unsigned)H_;
#pragma unroll
        for (int dj = 0; dj < 3; ++dj) {
          int nx = x + dj - 1;
          bool inb = yin && ((unsigned)nx < (unsigned)W_);
          int nidx = ny * W_ + nx;
          float cost;
          int si, sj;
          if (inb) {
            cost = cm[nidx];
            si = s0[nidx] + (1 - di);
            sj = s1[nidx] + (1 - dj);
          } else {
            cost = 10.0f;   // pad value of cost_map
            si = 11 - di;   // pad value 10 + (1 - di)
            sj = 11 - dj;
          }
          float e = __expf(-cost);  // T=1; range [e^-11,1], fp16-safe
          int ii = min(max(si, 0), H_ - 1);
          int jj = min(max(sj, 0), W_ - 1);
          unsigned int line = (unsigned int)(ii * W_ + jj);  // < 65536
          __half he = __float2half(e);
          unsigned short hb;
          __builtin_memcpy(&hb, &he, 2);
          u.ew[px][k * 9 + di * 3 + dj] = (line << 16) | (unsigned int)hb;
          psum += e;
        }
      }
      lds_part[px][k] = psum;  // denominator from f32 e's (exact)
    }
  }
  __threadfence();       // device-scope release for nt vt stores
  cg::this_grid().sync();  // all vt + ew + part ready

  // ---- stage B: 36-tap gather-sum, SADDR dwordx4, direct nt stores --------
  {
    int q = t & 3;        // 16B quad: channels 8q..8q+7
    int pxb = t >> 2;     // 0..31
    const char* base = (const char*)vt + ((size_t)b * HW_ << 6);
    unsigned int qoff = (unsigned int)(q << 4);
#pragma unroll 1
    for (int rep = 0; rep < 2; ++rep) {
      int px = pxb + 32 * rep;
      float acc[8] = {0.f, 0.f, 0.f, 0.f, 0.f, 0.f, 0.f, 0.f};
#pragma unroll
      for (int hb = 0; hb < 2; ++hb) {
        uint4 hv[18];
        float ewv[18];
#pragma unroll
        for (int m = 0; m < 18; ++m) {
          unsigned int wrd = u.ew[px][hb * 18 + m];  // broadcast ds_read_b32
          unsigned short lo = (unsigned short)(wrd & 0xffffu);
          __half he;
          __builtin_memcpy(&he, &lo, 2);
          ewv[m] = __half2float(he);
          unsigned int voff = ((wrd >> 16) << 6) + qoff;
          hv[m] = *(const uint4*)(base + voff);  // global_load_dwordx4 saddr
        }
#pragma unroll
        for (int m = 0; m < 18; ++m) {
          float e = ewv[m];
          __half2 h0, h1, h2, h3;
          __builtin_memcpy(&h0, &hv[m].x, 4);
          __builtin_memcpy(&h1, &hv[m].y, 4);
          __builtin_memcpy(&h2, &hv[m].z, 4);
          __builtin_memcpy(&h3, &hv[m].w, 4);
          float2 f0 = __half22float2(h0);
          float2 f1 = __half22float2(h1);
          float2 f2 = __half22float2(h2);
          float2 f3 = __half22float2(h3);
          acc[0] += e * f0.x; acc[1] += e * f0.y;
          acc[2] += e * f1.x; acc[3] += e * f1.y;
          acc[4] += e * f2.x; acc[5] += e * f2.y;
          acc[6] += e * f3.x; acc[7] += e * f3.y;
        }
      }
      float4 ps = *(const float4*)&lds_part[px][0];  // broadcast
      float inv = 1.0f / (ps.x + ps.y + ps.z + ps.w);
      size_t obase = (size_t)(b * C_) * HW_ + (size_t)y * W_ + x0 + px;
#pragma unroll
      for (int j = 0; j < 8; ++j) {
        __builtin_nontemporal_store(acc[j] * inv,
                                    &out[obase + (size_t)(8 * q + j) * HW_]);
      }
    }
  }
}

extern "C" void kernel_launch(void* const* d_in, const int* in_sizes, int n_in,
                              void* d_out, int out_size, void* d_ws, size_t ws_size,
                              hipStream_t stream) {
  const float* v = (const float*)d_in[0];
  const float* cost_map = (const float*)d_in[1];
  const int* shift_map = (const int*)d_in[2];
  float* out = (float*)d_out;
  unsigned int* vt = (unsigned int*)d_ws;  // 8.4 MB fp16 pixel-line buffer

  void* args[] = {(void*)&v, (void*)&cost_map, (void*)&shift_map,
                  (void*)&vt, (void*)&out};
  hipLaunchCooperativeKernel((const void*)fused_kernel, dim3(2048), dim3(128),
                             args, 0, stream);
}

// Round 12
// 48.206 us; speedup vs baseline: 6.1840x; 6.1840x over previous
//
#include <hip/hip_runtime.h>
#include <hip/hip_fp16.h>

#define B_ 2
#define C_ 32
#define H_ 256
#define W_ 256
#define K_ 4
#define HW_ (H_ * W_)

typedef float floatx4 __attribute__((ext_vector_type(4)));
typedef unsigned int uintx4 __attribute__((ext_vector_type(4)));

// ---------------------------------------------------------------------------
// Transpose+convert v (B,C,H,W) fp32 -> vt (B,H*W,C) fp16 (64B per pixel).
// ---------------------------------------------------------------------------
__global__ __launch_bounds__(256) void transpose_v_kernel(
    const float* __restrict__ v, unsigned int* __restrict__ vt) {
  __shared__ float tile[32][65];
  int t = threadIdx.x;
  int pix0 = blockIdx.x * 64;          // global pixel index in [0, B*HW)
  int b = pix0 >> 16;
  int pixb = pix0 & (HW_ - 1);
  const float* vb = v + (size_t)b * C_ * HW_;
  int c = t >> 3;
  int f = t & 7;
#pragma unroll
  for (int h = 0; h < 2; ++h) {
    int px = h * 32 + f * 4;
    floatx4 r = __builtin_nontemporal_load(
        (const floatx4*)&vb[(size_t)c * HW_ + pixb + px]);
    tile[c][px + 0] = r.x;
    tile[c][px + 1] = r.y;
    tile[c][px + 2] = r.z;
    tile[c][px + 3] = r.w;
  }
  __syncthreads();
  int px = t >> 2, q = t & 3;
  unsigned int w0, w1, w2, w3;
  { __half2 h2 = __floats2half2_rn(tile[8*q+0][px], tile[8*q+1][px]); __builtin_memcpy(&w0, &h2, 4); }
  { __half2 h2 = __floats2half2_rn(tile[8*q+2][px], tile[8*q+3][px]); __builtin_memcpy(&w1, &h2, 4); }
  { __half2 h2 = __floats2half2_rn(tile[8*q+4][px], tile[8*q+5][px]); __builtin_memcpy(&w2, &h2, 4); }
  { __half2 h2 = __floats2half2_rn(tile[8*q+6][px], tile[8*q+7][px]); __builtin_memcpy(&w3, &h2, 4); }
  uintx4 o;
  o.x = w0; o.y = w1; o.z = w2; o.w = w3;
  __builtin_nontemporal_store(
      o, (uintx4*)((char*)vt + ((size_t)(pix0 + px) << 6) + (q << 4)));
}

// ---------------------------------------------------------------------------
// Main kernel: ONE WAVE per block, 16 pixels of one row; 8192 blocks.
// XCD-batch partition (confirmed R4: FETCH 100->25MB): XCDs 0-3 own batch 0,
// XCDs 4-7 batch 1; each XCD's 4MiB vt slice is L2-resident.
// R12: force 18-deep load batches with sched_barrier(0) between the issue
// loop and the consume loop (R6/R10 evidence: compiler re-serialized to ~6
// in flight, VGPR_Count=52 — the latency x concurrency deficit IS the wall).
// launch_bounds(64,4): VGPR cap 128 (~110 needed), 16 waves/CU resident.
// Phase-1 cost/shift loads are nontemporal (evict-first) so streaming does
// not evict vt from L2.
// ---------------------------------------------------------------------------
__global__ __launch_bounds__(64, 4) void psatt_kernel(
    const float* __restrict__ cost_map, const int* __restrict__ shift_map,
    const unsigned int* __restrict__ vt, float* __restrict__ out) {
  __shared__ float2 lds_ew[16][37];  // (e, byte-off); [px][m] conflict-free
  __shared__ float lds_part[16][4];  // softmax partials per (px,k)
  __shared__ float lds_out[16][33];  // conflict-free epilogue transpose

  int t = threadIdx.x;
  // XCD-aware decomposition (empirical round-robin: XCD = blockIdx % 8).
  int bid = blockIdx.x;            // 0..8191
  int xcd = bid & 7;
  int slot = bid >> 3;             // 0..1023
  int b = xcd >> 2;                // XCDs 0-3 -> batch 0, 4-7 -> batch 1
  int workid = ((xcd & 3) << 10) + slot;  // 0..4095; 64 contiguous rows/XCD
  int y = workid >> 4;             // W/16 = 16 tiles per row
  int x0 = (workid & 15) << 4;

  // ---- phase 1: weights + line byte-offsets (nt: protect vt residency) ----
  {
    int k = t >> 4;   // 4 k-groups of 16 lanes
    int px = t & 15;
    int x = x0 + px;
    const float* cm = cost_map + (size_t)(b * K_ + k) * HW_;
    const int* s0 = shift_map + (size_t)((b * 2 + 0) * K_ + k) * HW_;
    const int* s1 = shift_map + (size_t)((b * 2 + 1) * K_ + k) * HW_;
    float psum = 0.f;
#pragma unroll
    for (int di = 0; di < 3; ++di) {
      int ny = y + di - 1;
      bool yin = (unsigned)ny < (unsigned)H_;
#pragma unroll
      for (int dj = 0; dj < 3; ++dj) {
        int nx = x + dj - 1;
        bool inb = yin && ((unsigned)nx < (unsigned)W_);
        int nidx = ny * W_ + nx;
        float cost;
        int si, sj;
        if (inb) {
          cost = __builtin_nontemporal_load(&cm[nidx]);
          si = __builtin_nontemporal_load(&s0[nidx]) + (1 - di);
          sj = __builtin_nontemporal_load(&s1[nidx]) + (1 - dj);
        } else {
          cost = 10.0f;     // pad value of cost_map
          si = 11 - di;     // pad value 10 + (1 - di)
          sj = 11 - dj;
        }
        float e = __expf(-cost);  // T = 1; no max-sub needed (range safe)
        int ii = min(max(si, 0), H_ - 1);
        int jj = min(max(sj, 0), W_ - 1);
        int m = k * 9 + di * 3 + dj;
        lds_ew[px][m] = make_float2(e, __int_as_float((ii * W_ + jj) << 6));
        psum += e;
      }
    }
    lds_part[px][k] = psum;
  }
  __syncthreads();  // intra-wave: just an LDS visibility fence

  // ---- phase 2: gather-sum; SADDR dwordx4; sched_barrier-pinned batches ---
  {
    int q = t & 3;      // 16B quad within pixel: channels 8q..8q+7
    int px = t >> 2;    // 0..15
    const char* base = (const char*)vt + ((size_t)b * HW_ << 6);  // SGPR base
    unsigned int qoff = (unsigned int)(q << 4);
    float acc[8] = {0.f, 0.f, 0.f, 0.f, 0.f, 0.f, 0.f, 0.f};
#pragma unroll
    for (int half = 0; half < 2; ++half) {
      uint4 hv[18];
      // issue all 18 loads; sched_barrier(0) forbids sinking any into the
      // consume loop -> 18 dwordx4 (72 VGPRs) genuinely in flight
#pragma unroll
      for (int m = 0; m < 18; ++m) {
        float2 eo = lds_ew[px][half * 18 + m];     // ds_read_b64
        unsigned int voff = (unsigned int)__float_as_int(eo.y) + qoff;
        hv[m] = *(const uint4*)(base + voff);      // global_load_dwordx4 saddr
      }
      __builtin_amdgcn_sched_barrier(0);
#pragma unroll
      for (int m = 0; m < 18; ++m) {
        float e = lds_ew[px][half * 18 + m].x;     // re-read: saves 18 VGPRs
        __half2 h0, h1, h2, h3;
        __builtin_memcpy(&h0, &hv[m].x, 4);
        __builtin_memcpy(&h1, &hv[m].y, 4);
        __builtin_memcpy(&h2, &hv[m].z, 4);
        __builtin_memcpy(&h3, &hv[m].w, 4);
        float2 f0 = __half22float2(h0);
        float2 f1 = __half22float2(h1);
        float2 f2 = __half22float2(h2);
        float2 f3 = __half22float2(h3);
        acc[0] += e * f0.x; acc[1] += e * f0.y;
        acc[2] += e * f1.x; acc[3] += e * f1.y;
        acc[4] += e * f2.x; acc[5] += e * f2.y;
        acc[6] += e * f3.x; acc[7] += e * f3.y;
      }
    }
    float4 ps = *(const float4*)&lds_part[px][0];  // broadcast
    float inv = 1.0f / (ps.x + ps.y + ps.z + ps.w);
#pragma unroll
    for (int j = 0; j < 8; ++j) {
      lds_out[px][8 * q + j] = acc[j] * inv;
    }
  }
  __syncthreads();

  // ---- epilogue: transpose to channel-major, nontemporal coalesced stores -
  {
    int px = t & 15;
#pragma unroll
    for (int it = 0; it < 8; ++it) {
      int c = (t >> 4) + it * 4;
      __builtin_nontemporal_store(
          lds_out[px][c],
          &out[((size_t)(b * C_ + c) * H_ + y) * W_ + x0 + px]);
    }
  }
}

extern "C" void kernel_launch(void* const* d_in, const int* in_sizes, int n_in,
                              void* d_out, int out_size, void* d_ws, size_t ws_size,
                              hipStream_t stream) {
  const float* v = (const float*)d_in[0];
  const float* cost_map = (const float*)d_in[1];
  const int* shift_map = (const int*)d_in[2];
  float* out = (float*)d_out;

  unsigned int* vt = (unsigned int*)d_ws;  // B*HW*16 uints = 8.4 MB
  const int grid = B_ * H_ * (W_ / 16);    // 8192 one-wave blocks

  transpose_v_kernel<<<B_ * HW_ / 64, 256, 0, stream>>>(v, vt);
  psatt_kernel<<<grid, 64, 0, stream>>>(cost_map, shift_map, vt, out);
}

// Round 13
// 40.577 us; speedup vs baseline: 7.3466x; 1.1880x over previous
//
#include <hip/hip_runtime.h>
#include <hip/hip_fp16.h>

#define B_ 2
#define C_ 32
#define H_ 256
#define W_ 256
#define K_ 4
#define HW_ (H_ * W_)

typedef float floatx4 __attribute__((ext_vector_type(4)));
typedef unsigned int uintx4 __attribute__((ext_vector_type(4)));

// ---------------------------------------------------------------------------
// Transpose+convert v (B,C,H,W) fp32 -> vt (B,H*W,C) fp16 (64B per pixel).
// ---------------------------------------------------------------------------
__global__ __launch_bounds__(256) void transpose_v_kernel(
    const float* __restrict__ v, unsigned int* __restrict__ vt) {
  __shared__ float tile[32][65];
  int t = threadIdx.x;
  int pix0 = blockIdx.x * 64;          // global pixel index in [0, B*HW)
  int b = pix0 >> 16;
  int pixb = pix0 & (HW_ - 1);
  const float* vb = v + (size_t)b * C_ * HW_;
  int c = t >> 3;
  int f = t & 7;
#pragma unroll
  for (int h = 0; h < 2; ++h) {
    int px = h * 32 + f * 4;
    floatx4 r = __builtin_nontemporal_load(
        (const floatx4*)&vb[(size_t)c * HW_ + pixb + px]);
    tile[c][px + 0] = r.x;
    tile[c][px + 1] = r.y;
    tile[c][px + 2] = r.z;
    tile[c][px + 3] = r.w;
  }
  __syncthreads();
  int px = t >> 2, q = t & 3;
  unsigned int w0, w1, w2, w3;
  { __half2 h2 = __floats2half2_rn(tile[8*q+0][px], tile[8*q+1][px]); __builtin_memcpy(&w0, &h2, 4); }
  { __half2 h2 = __floats2half2_rn(tile[8*q+2][px], tile[8*q+3][px]); __builtin_memcpy(&w1, &h2, 4); }
  { __half2 h2 = __floats2half2_rn(tile[8*q+4][px], tile[8*q+5][px]); __builtin_memcpy(&w2, &h2, 4); }
  { __half2 h2 = __floats2half2_rn(tile[8*q+6][px], tile[8*q+7][px]); __builtin_memcpy(&w3, &h2, 4); }
  uintx4 o;
  o.x = w0; o.y = w1; o.z = w2; o.w = w3;
  __builtin_nontemporal_store(
      o, (uintx4*)((char*)vt + ((size_t)(pix0 + px) << 6) + (q << 4)));
}

// ---------------------------------------------------------------------------
// Main kernel: ONE WAVE per block, 16 pixels of one row; 8192 blocks.
// Identical to R10 EXCEPT: launch_bounds(64,4) [VGPR cap 128 vs 85] and
// sched_barrier(0) between the 18-load issue loop and the consume loop —
// a clean A/B to test whether forcing 18 dwordx4 in flight (72 data VGPRs)
// breaks the ~44.4us plateau. Phase-1 loads are PLAIN (R12's nt loads
// discarded halo reuse and cost ~4us).
// XCD-batch partition kept (confirmed R4): each XCD's 4MiB vt slice is
// L2-resident (FETCH ~25MB = compulsory).
// ---------------------------------------------------------------------------
__global__ __launch_bounds__(64, 4) void psatt_kernel(
    const float* __restrict__ cost_map, const int* __restrict__ shift_map,
    const unsigned int* __restrict__ vt, float* __restrict__ out) {
  __shared__ float2 lds_ew[16][37];  // (e, byte-off); [px][m] conflict-free
  __shared__ float lds_part[16][4];  // softmax partials per (px,k)
  __shared__ float lds_out[16][33];  // conflict-free epilogue transpose

  int t = threadIdx.x;
  // XCD-aware decomposition (empirical round-robin: XCD = blockIdx % 8).
  int bid = blockIdx.x;            // 0..8191
  int xcd = bid & 7;
  int slot = bid >> 3;             // 0..1023
  int b = xcd >> 2;                // XCDs 0-3 -> batch 0, 4-7 -> batch 1
  int workid = ((xcd & 3) << 10) + slot;  // 0..4095; 64 contiguous rows/XCD
  int y = workid >> 4;             // W/16 = 16 tiles per row
  int x0 = (workid & 15) << 4;

  // ---- phase 1: weights + line byte-offsets (plain loads: halo reuse) -----
  {
    int k = t >> 4;   // 4 k-groups of 16 lanes
    int px = t & 15;
    int x = x0 + px;
    const float* cm = cost_map + (size_t)(b * K_ + k) * HW_;
    const int* s0 = shift_map + (size_t)((b * 2 + 0) * K_ + k) * HW_;
    const int* s1 = shift_map + (size_t)((b * 2 + 1) * K_ + k) * HW_;
    float psum = 0.f;
#pragma unroll
    for (int di = 0; di < 3; ++di) {
      int ny = y + di - 1;
      bool yin = (unsigned)ny < (unsigned)H_;
#pragma unroll
      for (int dj = 0; dj < 3; ++dj) {
        int nx = x + dj - 1;
        bool inb = yin && ((unsigned)nx < (unsigned)W_);
        int nidx = ny * W_ + nx;
        float cost;
        int si, sj;
        if (inb) {
          cost = cm[nidx];
          si = s0[nidx] + (1 - di);
          sj = s1[nidx] + (1 - dj);
        } else {
          cost = 10.0f;     // pad value of cost_map
          si = 11 - di;     // pad value 10 + (1 - di)
          sj = 11 - dj;
        }
        float e = __expf(-cost);  // T = 1; no max-sub needed (range safe)
        int ii = min(max(si, 0), H_ - 1);
        int jj = min(max(sj, 0), W_ - 1);
        int m = k * 9 + di * 3 + dj;
        lds_ew[px][m] = make_float2(e, __int_as_float((ii * W_ + jj) << 6));
        psum += e;
      }
    }
    lds_part[px][k] = psum;
  }
  __syncthreads();  // intra-wave: just an LDS visibility fence

  // ---- phase 2: gather-sum; SADDR dwordx4; sched_barrier-pinned batches ---
  {
    int q = t & 3;      // 16B quad within pixel: channels 8q..8q+7
    int px = t >> 2;    // 0..15
    const char* base = (const char*)vt + ((size_t)b * HW_ << 6);  // SGPR base
    unsigned int qoff = (unsigned int)(q << 4);
    float acc[8] = {0.f, 0.f, 0.f, 0.f, 0.f, 0.f, 0.f, 0.f};
#pragma unroll
    for (int half = 0; half < 2; ++half) {
      uint4 hv[18];
      // issue all 18 loads; sched_barrier(0) forbids sinking any into the
      // consume loop -> 18 dwordx4 (72 VGPRs) genuinely in flight
#pragma unroll
      for (int m = 0; m < 18; ++m) {
        float2 eo = lds_ew[px][half * 18 + m];     // ds_read_b64
        unsigned int voff = (unsigned int)__float_as_int(eo.y) + qoff;
        hv[m] = *(const uint4*)(base + voff);      // global_load_dwordx4 saddr
      }
      __builtin_amdgcn_sched_barrier(0);
#pragma unroll
      for (int m = 0; m < 18; ++m) {
        float e = lds_ew[px][half * 18 + m].x;     // re-read: saves 18 VGPRs
        __half2 h0, h1, h2, h3;
        __builtin_memcpy(&h0, &hv[m].x, 4);
        __builtin_memcpy(&h1, &hv[m].y, 4);
        __builtin_memcpy(&h2, &hv[m].z, 4);
        __builtin_memcpy(&h3, &hv[m].w, 4);
        float2 f0 = __half22float2(h0);
        float2 f1 = __half22float2(h1);
        float2 f2 = __half22float2(h2);
        float2 f3 = __half22float2(h3);
        acc[0] += e * f0.x; acc[1] += e * f0.y;
        acc[2] += e * f1.x; acc[3] += e * f1.y;
        acc[4] += e * f2.x; acc[5] += e * f2.y;
        acc[6] += e * f3.x; acc[7] += e * f3.y;
      }
    }
    float4 ps = *(const float4*)&lds_part[px][0];  // broadcast
    float inv = 1.0f / (ps.x + ps.y + ps.z + ps.w);
#pragma unroll
    for (int j = 0; j < 8; ++j) {
      lds_out[px][8 * q + j] = acc[j] * inv;
    }
  }
  __syncthreads();

  // ---- epilogue: transpose to channel-major, nontemporal coalesced stores -
  {
    int px = t & 15;
#pragma unroll
    for (int it = 0; it < 8; ++it) {
      int c = (t >> 4) + it * 4;
      __builtin_nontemporal_store(
          lds_out[px][c],
          &out[((size_t)(b * C_ + c) * H_ + y) * W_ + x0 + px]);
    }
  }
}

extern "C" void kernel_launch(void* const* d_in, const int* in_sizes, int n_in,
                              void* d_out, int out_size, void* d_ws, size_t ws_size,
                              hipStream_t stream) {
  const float* v = (const float*)d_in[0];
  const float* cost_map = (const float*)d_in[1];
  const int* shift_map = (const int*)d_in[2];
  float* out = (float*)d_out;

  unsigned int* vt = (unsigned int*)d_ws;  // B*HW*16 uints = 8.4 MB
  const int grid = B_ * H_ * (W_ / 16);    // 8192 one-wave blocks

  transpose_v_kernel<<<B_ * HW_ / 64, 256, 0, stream>>>(v, vt);
  psatt_kernel<<<grid, 64, 0, stream>>>(cost_map, shift_map, vt, out);
}